// Round 2
// baseline (3772.098 us; speedup 1.0000x reference)
//
#include <hip/hip_runtime.h>
#include <stdint.h>

#define NROWS   131072
#define DDIM    256
#define BM      128
#define BN      160
#define BK      64
#define NTILE_R (NROWS / BM)          // 1024
#define NTILE_C 8                     // 1280 / 160
#define NWG     (NTILE_R * NTILE_C)   // 8192
#define NELEM   ((size_t)NROWS * DDIM)

typedef __attribute__((ext_vector_type(8))) short  vbf16x8;   // 8 bf16 in 4 VGPRs
typedef __attribute__((ext_vector_type(4))) float  vf32x4;
typedef __attribute__((ext_vector_type(4))) unsigned int vu32x4;

struct Params {
  const float *x, *lh, *rh, *lc, *rc;
  // weight table [segment][gate]; gates: 0=u 1=i 2=lf 3=rf 4=o
  const float *s0g0, *s0g1, *s0g2, *s0g3, *s0g4;   // seg0: x-side  W_cx W_ix W_fx W_fx W_ox
  const float *s1g0, *s1g1, *s1g2, *s1g3, *s1g4;   // seg1: lh-side U_ulh U_ilh U_lflh U_rflh U_olh
  const float *s2g0, *s2g1, *s2g2, *s2g3, *s2g4;   // seg2: rh-side U_urh U_irh U_lfrh U_rfrh U_orh
  const float *bcx, *bix, *bfx, *box;
  float *out;
};

// pack two fp32 -> one u32 holding 2 bf16 (truncation; absmax was 0.03 vs 0.14 thr)
__device__ __forceinline__ unsigned pk2(float hi, float lo) {
  return __builtin_amdgcn_perm(__float_as_uint(hi), __float_as_uint(lo), 0x07060302u);
}
__device__ __forceinline__ float sigm(float v)  { return 1.f / (1.f + __expf(-v)); }
__device__ __forceinline__ float tanh_(float v) { return 1.f - 2.f / (1.f + __expf(2.f * v)); }

// Single-buffered LDS (36 KiB) -> 4 blocks/CU (vs 72 KiB / 2 blocks in R1).
// T14 split: loads for t+1 issued before compute(t); raw s_barrier (no vmcnt
// drain) between compute and the pack/ds_write so loads stay in flight and the
// compiler emits counted vmcnt at first register use.
__global__ __launch_bounds__(256, 4) void fused_tree_cell(Params p)
{
  const int t   = threadIdx.x;
  const int bid = blockIdx.x;
  // XCD-bijective swizzle: col-tile fastest within an XCD chunk -> the 4
  // co-resident blocks/CU share one A row-panel (L1/L2 hits).
  const int nbid    = (bid & 7) * (NWG / 8) + (bid >> 3);
  const int tileRow = nbid >> 3;        // 0..1023
  const int cb      = nbid & 7;         // 0..7 (col-tile: 160 permuted cols)
  const int rowBase = tileRow * BM;

  __shared__ short As[BM * BK];         // 16 KiB
  __shared__ short Bs[BN * BK];         // 20 KiB

  const int l  = t & 63;
  const int lm = l & 15;                // frag row/col
  const int lk = l >> 4;                // k-group
  const int w  = t >> 6;
  const int wr = w >> 1;                // wave row 0..1  (64 rows each)
  const int wc = w & 1;                 // wave col 0..1  (80 cols each)

  vf32x4 acc[4][5];
#pragma unroll
  for (int m = 0; m < 4; ++m)
#pragma unroll
    for (int n = 0; n < 5; ++n) acc[m][n] = (vf32x4)(0.f);

  float4 aR[4][2];                      // staged A fp32 (32 VGPR)
  float4 bR[5][2];                      // staged B fp32 (40 VGPR)

  const int tg  = t >> 3;               // 0..31: row within a staging pass
  const int kc  = (t & 7) * 8;          // elem col within BK
  const int kcB = kc * 2;               // byte col within LDS row

  auto stage_load = [&](int kt) {
    const int seg  = kt >> 2;           // K segment (x / lh / rh)
    const int ksub = (kt & 3) * 64;
    const float *ap, *g0, *g1, *g2, *g3, *g4;
    if (seg == 0)      { ap = p.x;  g0 = p.s0g0; g1 = p.s0g1; g2 = p.s0g2; g3 = p.s0g3; g4 = p.s0g4; }
    else if (seg == 1) { ap = p.lh; g0 = p.s1g0; g1 = p.s1g1; g2 = p.s1g2; g3 = p.s1g3; g4 = p.s1g4; }
    else               { ap = p.rh; g0 = p.s2g0; g1 = p.s2g1; g2 = p.s2g2; g3 = p.s2g3; g4 = p.s2g4; }
#pragma unroll
    for (int ps = 0; ps < 4; ++ps) {    // A: 128 rows, 32 rows/pass
      const float* s = ap + (size_t)(rowBase + ps * 32 + tg) * DDIM + ksub + kc;
      aR[ps][0] = *(const float4*)s;
      aR[ps][1] = *(const float4*)(s + 4);
    }
    // B: permuted rows n = ps*32+tg; gate g=(n/16)%5 -> compile-time pair per
    // pass selected by t bit7; d = (n>=80)*16 + (n&15), global d = cb*32 + d.
#define BLOAD(ps, GA, GB) { \
    const float* bp = (t & 128) ? (GB) : (GA); \
    const int dloc = ((((ps) * 32) + tg) >= 80 ? 16 : 0) + (tg & 15); \
    const float* s = bp + (size_t)(cb * 32 + dloc) * DDIM + ksub + kc; \
    bR[ps][0] = *(const float4*)s; \
    bR[ps][1] = *(const float4*)(s + 4); }
    BLOAD(0, g0, g1)
    BLOAD(1, g2, g3)
    BLOAD(2, g4, g0)
    BLOAD(3, g1, g2)
    BLOAD(4, g3, g4)
#undef BLOAD
  };

  auto stage_write = [&]() {
    char* Ab = (char*)&As[0];
#pragma unroll
    for (int ps = 0; ps < 4; ++ps) {
      const int row  = ps * 32 + tg;
      const int byte = (row * 128 + kcB) ^ ((row & 7) << 4);   // T2 XOR swizzle
      vu32x4 v = { pk2(aR[ps][0].y, aR[ps][0].x), pk2(aR[ps][0].w, aR[ps][0].z),
                   pk2(aR[ps][1].y, aR[ps][1].x), pk2(aR[ps][1].w, aR[ps][1].z) };
      *(vu32x4*)(Ab + byte) = v;
    }
    char* Bb = (char*)&Bs[0];
#pragma unroll
    for (int ps = 0; ps < 5; ++ps) {
      const int row  = ps * 32 + tg;
      const int byte = (row * 128 + kcB) ^ ((row & 7) << 4);
      vu32x4 v = { pk2(bR[ps][0].y, bR[ps][0].x), pk2(bR[ps][0].w, bR[ps][0].z),
                   pk2(bR[ps][1].y, bR[ps][1].x), pk2(bR[ps][1].w, bR[ps][1].z) };
      *(vu32x4*)(Bb + byte) = v;
    }
  };

  auto compute = [&]() {
    const char* Ab = (const char*)&As[0];
    const char* Bb = (const char*)&Bs[0];
    __builtin_amdgcn_s_setprio(1);
#pragma unroll
    for (int ks = 0; ks < 2; ++ks) {
      vbf16x8 af[4], bf[5];
#pragma unroll
      for (int m = 0; m < 4; ++m) {
        const int row  = wr * 64 + m * 16 + lm;
        const int byte = (row * 128 + ks * 64 + lk * 16) ^ ((row & 7) << 4);
        af[m] = *(const vbf16x8*)(Ab + byte);
      }
#pragma unroll
      for (int n = 0; n < 5; ++n) {
        const int row  = wc * 80 + n * 16 + lm;
        const int byte = (row * 128 + ks * 64 + lk * 16) ^ ((row & 7) << 4);
        bf[n] = *(const vbf16x8*)(Bb + byte);
      }
#pragma unroll
      for (int m = 0; m < 4; ++m)
#pragma unroll
        for (int n = 0; n < 5; ++n)
          acc[m][n] = __builtin_amdgcn_mfma_f32_16x16x32_bf16(af[m], bf[n], acc[m][n], 0, 0, 0);
    }
    __builtin_amdgcn_s_setprio(0);
  };

  // prologue
  stage_load(0);
  stage_write();
  __syncthreads();

  // K loop: 768 / 64 = 12 tiles, single LDS buffer, split barriers.
  for (int kt = 0; kt < 12; ++kt) {
    if (kt < 11) stage_load(kt + 1);    // issue early: latency hides under MFMA
    compute();
    if (kt < 11) {
      __builtin_amdgcn_sched_barrier(0);   // pin ds_reads/MFMA before barrier
      __builtin_amdgcn_s_barrier();        // readers done; NO vmcnt drain here
      stage_write();                        // counted vmcnt at first reg use
      __syncthreads();                      // writes visible for next compute
    }
  }

  // ---- fused epilogue: all 5 gates for this (row, d) live in acc[m][0..4] ----
  const int dcol = cb * 32 + wc * 16 + lm;
  const float bu  = p.bcx[dcol];
  const float bi  = p.bix[dcol];
  const float bff = p.bfx[dcol];
  const float bo  = p.box[dcol];
#pragma unroll
  for (int m = 0; m < 4; ++m) {
    const int r0 = rowBase + wr * 64 + m * 16 + lk * 4;
#pragma unroll
    for (int j = 0; j < 4; ++j) {
      const size_t off = (size_t)(r0 + j) * DDIM + dcol;
      const float pu  = acc[m][0][j] + bu;
      const float pi  = acc[m][1][j] + bi;
      const float plf = acc[m][2][j] + bff;
      const float prf = acc[m][3][j] + bff;
      const float po  = acc[m][4][j] + bo;
      const float u  = tanh_(pu);
      const float ig = sigm(pi);
      const float lf = sigm(plf);
      const float rf = sigm(prf);
      const float og = sigm(po);
      const float c  = ig * u + lf * p.lc[off] + rf * p.rc[off];
      const float h  = og * tanh_(c);
      p.out[off]         = c;
      p.out[NELEM + off] = h;
    }
  }
}

extern "C" void kernel_launch(void* const* d_in, const int* in_sizes, int n_in,
                              void* d_out, int out_size, void* d_ws, size_t ws_size,
                              hipStream_t stream)
{
  Params p;
  p.x  = (const float*)d_in[0];
  p.lc = (const float*)d_in[1];
  p.lh = (const float*)d_in[2];
  p.rc = (const float*)d_in[3];
  p.rh = (const float*)d_in[4];
  const float* W_cx = (const float*)d_in[5];
  const float* b_cx = (const float*)d_in[6];
  const float* W_ox = (const float*)d_in[7];
  const float* b_ox = (const float*)d_in[8];
  const float* W_fx = (const float*)d_in[9];
  const float* b_fx = (const float*)d_in[10];
  const float* W_ix = (const float*)d_in[11];
  const float* b_ix = (const float*)d_in[12];
  const float* U_ilh  = (const float*)d_in[13];
  const float* U_irh  = (const float*)d_in[14];
  const float* U_lflh = (const float*)d_in[15];
  const float* U_lfrh = (const float*)d_in[16];
  const float* U_rflh = (const float*)d_in[17];
  const float* U_rfrh = (const float*)d_in[18];
  const float* U_ulh  = (const float*)d_in[19];
  const float* U_urh  = (const float*)d_in[20];
  const float* U_olh  = (const float*)d_in[21];
  const float* U_orh  = (const float*)d_in[22];

  // gates: 0=u 1=i 2=lf 3=rf 4=o
  p.s0g0 = W_cx;  p.s0g1 = W_ix;  p.s0g2 = W_fx;   p.s0g3 = W_fx;   p.s0g4 = W_ox;
  p.s1g0 = U_ulh; p.s1g1 = U_ilh; p.s1g2 = U_lflh; p.s1g3 = U_rflh; p.s1g4 = U_olh;
  p.s2g0 = U_urh; p.s2g1 = U_irh; p.s2g2 = U_lfrh; p.s2g3 = U_rfrh; p.s2g4 = U_orh;
  p.bcx = b_cx; p.bix = b_ix; p.bfx = b_fx; p.box = b_ox;
  p.out = (float*)d_out;

  hipLaunchKernelGGL(fused_tree_cell, dim3(NWG), dim3(256), 0, stream, p);
}

// Round 3
// 579.248 us; speedup vs baseline: 6.5121x; 6.5121x over previous
//
#include <hip/hip_runtime.h>
#include <stdint.h>

#define NROWS   131072
#define DDIM    256
#define BM      128
#define BN      160
#define BK      64
#define NTILE_R (NROWS / BM)          // 1024
#define NTILE_C 8                     // 1280 / 160
#define NWG     (NTILE_R * NTILE_C)   // 8192
#define NELEM   ((size_t)NROWS * DDIM)

typedef __attribute__((ext_vector_type(8))) short  vbf16x8;   // 8 bf16 in 4 VGPRs
typedef __attribute__((ext_vector_type(4))) float  vf32x4;
typedef __attribute__((ext_vector_type(4))) unsigned int vu32x4;

struct Params {
  const float *x, *lh, *rh, *lc, *rc;
  // weight table [segment][gate]; gates: 0=u 1=i 2=lf 3=rf 4=o
  const float *s0g0, *s0g1, *s0g2, *s0g3, *s0g4;   // seg0: x-side  W_cx W_ix W_fx W_fx W_ox
  const float *s1g0, *s1g1, *s1g2, *s1g3, *s1g4;   // seg1: lh-side U_ulh U_ilh U_lflh U_rflh U_olh
  const float *s2g0, *s2g1, *s2g2, *s2g3, *s2g4;   // seg2: rh-side U_urh U_irh U_lfrh U_rfrh U_orh
  const float *bcx, *bix, *bfx, *box;
  float *out;
};

// pack two fp32 -> one u32 holding 2 bf16 (truncation; absmax 0.03 vs 0.14 thr)
__device__ __forceinline__ unsigned pk2(float hi, float lo) {
  return __builtin_amdgcn_perm(__float_as_uint(hi), __float_as_uint(lo), 0x07060302u);
}
__device__ __forceinline__ float sigm(float v)  { return 1.f / (1.f + __expf(-v)); }
__device__ __forceinline__ float tanh_(float v) { return 1.f - 2.f / (1.f + __expf(2.f * v)); }

// Single-buffered LDS (36 KiB): LDS allows 4 blocks/CU. launch_bounds(256,2)
// (NOT 4 — R2 proved min-waves=4 caps VGPR at 128 and spills to scratch,
// 64 VGPR + 8.7 GB scratch writes + 6x slowdown). With the compiler's natural
// ~116 VGPR, 4 waves/SIMD fit anyway -> 4 blocks/CU co-resident.
__global__ __launch_bounds__(256, 2) void fused_tree_cell(Params p)
{
  const int t   = threadIdx.x;
  const int bid = blockIdx.x;
  // XCD-bijective swizzle: col-tile fastest within an XCD chunk -> co-resident
  // blocks share one A row-panel (L1/L2 hits).
  const int nbid    = (bid & 7) * (NWG / 8) + (bid >> 3);
  const int tileRow = nbid >> 3;        // 0..1023
  const int cb      = nbid & 7;         // 0..7 (col-tile: 160 permuted cols)
  const int rowBase = tileRow * BM;

  __shared__ short As[BM * BK];         // 16 KiB
  __shared__ short Bs[BN * BK];         // 20 KiB

  const int l  = t & 63;
  const int lm = l & 15;                // frag row/col
  const int lk = l >> 4;                // k-group
  const int w  = t >> 6;
  const int wr = w >> 1;                // wave row 0..1  (64 rows each)
  const int wc = w & 1;                 // wave col 0..1  (80 cols each)

  vf32x4 acc[4][5];
#pragma unroll
  for (int m = 0; m < 4; ++m)
#pragma unroll
    for (int n = 0; n < 5; ++n) acc[m][n] = (vf32x4)(0.f);

  float4 aR[4][2];                      // staged A fp32 (32 VGPR)
  float4 bR[5][2];                      // staged B fp32 (40 VGPR)

  const int tg  = t >> 3;               // 0..31: row within a staging pass
  const int kc  = (t & 7) * 8;          // elem col within BK
  const int kcB = kc * 2;               // byte col within LDS row

  auto stage_load = [&](int kt) {
    const int seg  = kt >> 2;           // K segment (x / lh / rh)
    const int ksub = (kt & 3) * 64;
    const float *ap, *g0, *g1, *g2, *g3, *g4;
    if (seg == 0)      { ap = p.x;  g0 = p.s0g0; g1 = p.s0g1; g2 = p.s0g2; g3 = p.s0g3; g4 = p.s0g4; }
    else if (seg == 1) { ap = p.lh; g0 = p.s1g0; g1 = p.s1g1; g2 = p.s1g2; g3 = p.s1g3; g4 = p.s1g4; }
    else               { ap = p.rh; g0 = p.s2g0; g1 = p.s2g1; g2 = p.s2g2; g3 = p.s2g3; g4 = p.s2g4; }
#pragma unroll
    for (int ps = 0; ps < 4; ++ps) {    // A: 128 rows, 32 rows/pass
      const float* s = ap + (size_t)(rowBase + ps * 32 + tg) * DDIM + ksub + kc;
      aR[ps][0] = *(const float4*)s;
      aR[ps][1] = *(const float4*)(s + 4);
    }
    // B: permuted rows n = ps*32+tg; gate g=(n/16)%5 -> compile-time pair per
    // pass selected by t bit7; d = (n>=80)*16 + (n&15), global d = cb*32 + d.
#define BLOAD(ps, GA, GB) { \
    const float* bp = (t & 128) ? (GB) : (GA); \
    const int dloc = ((((ps) * 32) + tg) >= 80 ? 16 : 0) + (tg & 15); \
    const float* s = bp + (size_t)(cb * 32 + dloc) * DDIM + ksub + kc; \
    bR[ps][0] = *(const float4*)s; \
    bR[ps][1] = *(const float4*)(s + 4); }
    BLOAD(0, g0, g1)
    BLOAD(1, g2, g3)
    BLOAD(2, g4, g0)
    BLOAD(3, g1, g2)
    BLOAD(4, g3, g4)
#undef BLOAD
  };

  auto stage_write = [&]() {
    char* Ab = (char*)&As[0];
#pragma unroll
    for (int ps = 0; ps < 4; ++ps) {
      const int row  = ps * 32 + tg;
      const int byte = (row * 128 + kcB) ^ ((row & 7) << 4);   // T2 XOR swizzle
      vu32x4 v = { pk2(aR[ps][0].y, aR[ps][0].x), pk2(aR[ps][0].w, aR[ps][0].z),
                   pk2(aR[ps][1].y, aR[ps][1].x), pk2(aR[ps][1].w, aR[ps][1].z) };
      *(vu32x4*)(Ab + byte) = v;
    }
    char* Bb = (char*)&Bs[0];
#pragma unroll
    for (int ps = 0; ps < 5; ++ps) {
      const int row  = ps * 32 + tg;
      const int byte = (row * 128 + kcB) ^ ((row & 7) << 4);
      vu32x4 v = { pk2(bR[ps][0].y, bR[ps][0].x), pk2(bR[ps][0].w, bR[ps][0].z),
                   pk2(bR[ps][1].y, bR[ps][1].x), pk2(bR[ps][1].w, bR[ps][1].z) };
      *(vu32x4*)(Bb + byte) = v;
    }
  };

  auto compute = [&]() {
    const char* Ab = (const char*)&As[0];
    const char* Bb = (const char*)&Bs[0];
    __builtin_amdgcn_s_setprio(1);
#pragma unroll
    for (int ks = 0; ks < 2; ++ks) {
      vbf16x8 af[4], bf[5];
#pragma unroll
      for (int m = 0; m < 4; ++m) {
        const int row  = wr * 64 + m * 16 + lm;
        const int byte = (row * 128 + ks * 64 + lk * 16) ^ ((row & 7) << 4);
        af[m] = *(const vbf16x8*)(Ab + byte);
      }
#pragma unroll
      for (int n = 0; n < 5; ++n) {
        const int row  = wc * 80 + n * 16 + lm;
        const int byte = (row * 128 + ks * 64 + lk * 16) ^ ((row & 7) << 4);
        bf[n] = *(const vbf16x8*)(Bb + byte);
      }
#pragma unroll
      for (int m = 0; m < 4; ++m)
#pragma unroll
        for (int n = 0; n < 5; ++n)
          acc[m][n] = __builtin_amdgcn_mfma_f32_16x16x32_bf16(af[m], bf[n], acc[m][n], 0, 0, 0);
    }
    __builtin_amdgcn_s_setprio(0);
  };

  // prologue
  stage_load(0);
  stage_write();
  __syncthreads();

  // K loop: 768 / 64 = 12 tiles, single LDS buffer, split barriers (T14).
  for (int kt = 0; kt < 12; ++kt) {
    if (kt < 11) stage_load(kt + 1);    // issue early: latency hides under MFMA
    compute();
    if (kt < 11) {
      __builtin_amdgcn_sched_barrier(0);   // pin ds_reads/MFMA before barrier
      __builtin_amdgcn_s_barrier();        // readers done; NO vmcnt drain here
      stage_write();                        // counted vmcnt at first reg use
      __syncthreads();                      // writes visible for next compute
    }
  }

  // ---- fused epilogue: all 5 gates for this (row, d) live in acc[m][0..4] ----
  const int dcol = cb * 32 + wc * 16 + lm;
  const float bu  = p.bcx[dcol];
  const float bi  = p.bix[dcol];
  const float bff = p.bfx[dcol];
  const float bo  = p.box[dcol];
#pragma unroll
  for (int m = 0; m < 4; ++m) {
    const int r0 = rowBase + wr * 64 + m * 16 + lk * 4;
#pragma unroll
    for (int j = 0; j < 4; ++j) {
      const size_t off = (size_t)(r0 + j) * DDIM + dcol;
      const float pu  = acc[m][0][j] + bu;
      const float pi  = acc[m][1][j] + bi;
      const float plf = acc[m][2][j] + bff;
      const float prf = acc[m][3][j] + bff;
      const float po  = acc[m][4][j] + bo;
      const float u  = tanh_(pu);
      const float ig = sigm(pi);
      const float lf = sigm(plf);
      const float rf = sigm(prf);
      const float og = sigm(po);
      const float c  = ig * u + lf * p.lc[off] + rf * p.rc[off];
      const float h  = og * tanh_(c);
      p.out[off]         = c;
      p.out[NELEM + off] = h;
    }
  }
}

extern "C" void kernel_launch(void* const* d_in, const int* in_sizes, int n_in,
                              void* d_out, int out_size, void* d_ws, size_t ws_size,
                              hipStream_t stream)
{
  Params p;
  p.x  = (const float*)d_in[0];
  p.lc = (const float*)d_in[1];
  p.lh = (const float*)d_in[2];
  p.rc = (const float*)d_in[3];
  p.rh = (const float*)d_in[4];
  const float* W_cx = (const float*)d_in[5];
  const float* b_cx = (const float*)d_in[6];
  const float* W_ox = (const float*)d_in[7];
  const float* b_ox = (const float*)d_in[8];
  const float* W_fx = (const float*)d_in[9];
  const float* b_fx = (const float*)d_in[10];
  const float* W_ix = (const float*)d_in[11];
  const float* b_ix = (const float*)d_in[12];
  const float* U_ilh  = (const float*)d_in[13];
  const float* U_irh  = (const float*)d_in[14];
  const float* U_lflh = (const float*)d_in[15];
  const float* U_lfrh = (const float*)d_in[16];
  const float* U_rflh = (const float*)d_in[17];
  const float* U_rfrh = (const float*)d_in[18];
  const float* U_ulh  = (const float*)d_in[19];
  const float* U_urh  = (const float*)d_in[20];
  const float* U_olh  = (const float*)d_in[21];
  const float* U_orh  = (const float*)d_in[22];

  // gates: 0=u 1=i 2=lf 3=rf 4=o
  p.s0g0 = W_cx;  p.s0g1 = W_ix;  p.s0g2 = W_fx;   p.s0g3 = W_fx;   p.s0g4 = W_ox;
  p.s1g0 = U_ulh; p.s1g1 = U_ilh; p.s1g2 = U_lflh; p.s1g3 = U_rflh; p.s1g4 = U_olh;
  p.s2g0 = U_urh; p.s2g1 = U_irh; p.s2g2 = U_lfrh; p.s2g3 = U_rfrh; p.s2g4 = U_orh;
  p.bcx = b_cx; p.bix = b_ix; p.bfx = b_fx; p.box = b_ox;
  p.out = (float*)d_out;

  hipLaunchKernelGGL(fused_tree_cell, dim3(NWG), dim3(256), 0, stream, p);
}